// Round 5
// baseline (402.693 us; speedup 1.0000x reference)
//
#include <hip/hip_runtime.h>
#include <math.h>

#define B_ROWS 65536
#define WDIM 512
#define HDIM 8
#define THREADS 512

// Native clang vector type — __builtin_nontemporal_{load,store} require it.
typedef float native_float4 __attribute__((ext_vector_type(4)));

// ---- DPP cross-lane (VALU pipe; avoids ds_swizzle latency/contention) ----
template<int CTRL, int ROWM>
__device__ __forceinline__ float dpp_mov(float oldv, float x) {
    return __int_as_float(__builtin_amdgcn_update_dpp(
        __float_as_int(oldv), __float_as_int(x), CTRL, ROWM, 0xF, false));
}

// Full-wave (64-lane) sum, broadcast via readlane(63). Order bit-exact vs R0.
__device__ __forceinline__ float wave_sum(float x) {
    x += dpp_mov<0x121, 0xF>(0.f, x);   // row_ror:1
    x += dpp_mov<0x122, 0xF>(0.f, x);   // row_ror:2
    x += dpp_mov<0x124, 0xF>(0.f, x);   // row_ror:4
    x += dpp_mov<0x128, 0xF>(0.f, x);   // row_ror:8  -> row-of-16 sums
    x += dpp_mov<0x142, 0xA>(0.f, x);   // row_bcast15
    x += dpp_mov<0x143, 0xC>(0.f, x);   // row_bcast31 -> lane63 = total
    return __int_as_float(__builtin_amdgcn_readlane(__float_as_int(x), 63));
}

__device__ __forceinline__ float wave_max(float x) {
    x = fmaxf(x, dpp_mov<0x121, 0xF>(-INFINITY, x));
    x = fmaxf(x, dpp_mov<0x122, 0xF>(-INFINITY, x));
    x = fmaxf(x, dpp_mov<0x124, 0xF>(-INFINITY, x));
    x = fmaxf(x, dpp_mov<0x128, 0xF>(-INFINITY, x));
    x = fmaxf(x, dpp_mov<0x142, 0xA>(-INFINITY, x));
    x = fmaxf(x, dpp_mov<0x143, 0xC>(-INFINITY, x));
    return __int_as_float(__builtin_amdgcn_readlane(__float_as_int(x), 63));
}

__device__ __forceinline__ float dot8(native_float4 a0, native_float4 a1,
                                      native_float4 b0, native_float4 b1) {
    float s = a0.x * b0.x;
    s = fmaf(a0.y, b0.y, s); s = fmaf(a0.z, b0.z, s); s = fmaf(a0.w, b0.w, s);
    s = fmaf(a1.x, b1.x, s); s = fmaf(a1.y, b1.y, s);
    s = fmaf(a1.z, b1.z, s); s = fmaf(a1.w, b1.w, s);
    return s;
}

// R5: occupancy is the never-moved lever. Measured: every prior config gave
// 16 waves/CU — 2-row ILP's true demand (~100 VGPR) rounds to the 128 HW
// quantum -> 4 waves/SIMD. HW gives 8 waves/SIMD only at VGPR<=64 (m69
// quantum steps 64/128/256). 1 row/wave + no prefetch has demand ~50-56:
// fits the (512,4) compiler cap of 256/4=64 (measured rule) with slack ->
// no spill, VGPR<=64 -> 8 waves/SIMD; LDS 34,816B -> 4 blocks x 8 = 32
// waves/CU (HW max). TLP (8 waves/SIMD) replaces the 2-row ILP.
__global__ __launch_bounds__(THREADS, 4)
void fused_mlp_topk(const float* __restrict__ x,
                    const float* __restrict__ W1,
                    const float* __restrict__ b1,
                    const float* __restrict__ W2,
                    const float* __restrict__ b2,
                    const float* __restrict__ W3,
                    const float* __restrict__ b3,
                    float* __restrict__ out)
{
    // W1 as [j][i] (8x512), W3 transposed to [k][i] (8x512): compute reads are
    // 16B/lane stride-16B ds_read_b128 (conflict-free).
    __shared__ __align__(16) float sW1[HDIM * WDIM];
    __shared__ __align__(16) float sW3t[HDIM * WDIM];
    __shared__ __align__(16) float sb3[WDIM];

    const int tid = threadIdx.x;
    for (int i = tid; i < HDIM * WDIM; i += THREADS) sW1[i] = W1[i];
    for (int i = tid; i < HDIM * WDIM; i += THREADS) {
        int r = i >> 3, k = i & 7;          // W3 is (512,8) row-major
        sW3t[k * WDIM + r] = W3[i];
    }
    for (int i = tid; i < WDIM; i += THREADS) sb3[i] = b3[i];
    __syncthreads();

    const int lane = tid & 63;
    const int wave_id = blockIdx.x * (THREADS / 64) + (tid >> 6);   // 8192 waves

    const native_float4* sW1v = reinterpret_cast<const native_float4*>(sW1);
    const native_float4* sW3v = reinterpret_cast<const native_float4*>(sW3t);
    const native_float4* sb3v = reinterpret_cast<const native_float4*>(sb3);

    int ra = wave_id;                       // rows: wave_id + it*8192

    #pragma unroll 1
    for (int it = 0; it < 8; ++it) {        // 8192 waves * 1 row * 8 = 65536
        // -------- load this row's x (non-temporal; TLP hides latency) ----
        const native_float4* xp = reinterpret_cast<const native_float4*>(x + (size_t)ra * WDIM);
        native_float4 x0 = __builtin_nontemporal_load(xp + lane);
        native_float4 x1 = __builtin_nontemporal_load(xp + lane + 64);

        // -------- layer 1: 8 dots of 512 --------
        float pa[HDIM];
        #pragma unroll
        for (int j = 0; j < HDIM; ++j) {
            native_float4 w0 = sW1v[j * 128 + lane];
            native_float4 w1 = sW1v[j * 128 + lane + 64];
            pa[j] = dot8(x0, x1, w0, w1);
        }
        float h1[HDIM];
        #pragma unroll
        for (int j = 0; j < HDIM; ++j) {
            float sa = wave_sum(pa[j]) + b1[j];
            h1[j] = sa > 0.f ? sa : 0.f;
        }

        // -------- layer 2: 8x8, wave-uniform --------
        float h2[HDIM];
        #pragma unroll
        for (int j = 0; j < HDIM; ++j) {
            float va = b2[j];
            #pragma unroll
            for (int k = 0; k < HDIM; ++k) {
                const float w = W2[j * HDIM + k];
                va = fmaf(w, h1[k], va);
            }
            h2[j] = va > 0.f ? va : 0.f;
        }

        // -------- layer 3: y = h2 . W3t[:, i] + b3 ------
        native_float4 y0 = sb3v[lane];
        native_float4 y1 = sb3v[lane + 64];
        #pragma unroll
        for (int k = 0; k < HDIM; ++k) {
            const float ha = h2[k];
            native_float4 w0 = sW3v[k * 128 + lane];
            native_float4 w1 = sW3v[k * 128 + lane + 64];
            y0.x = fmaf(ha, w0.x, y0.x); y0.y = fmaf(ha, w0.y, y0.y);
            y0.z = fmaf(ha, w0.z, y0.z); y0.w = fmaf(ha, w0.w, y0.w);
            y1.x = fmaf(ha, w1.x, y1.x); y1.y = fmaf(ha, w1.y, y1.y);
            y1.z = fmaf(ha, w1.z, y1.z); y1.w = fmaf(ha, w1.w, y1.w);
        }

        // -------- softmax (numerics bit-identical to prior rounds) --------
        float lma = fmaxf(fmaxf(fmaxf(y0.x, y0.y), fmaxf(y0.z, y0.w)),
                          fmaxf(fmaxf(y1.x, y1.y), fmaxf(y1.z, y1.w)));
        float ma = wave_max(lma);

        float p[8];
        p[0] = expf(y0.x - ma); p[1] = expf(y0.y - ma);
        p[2] = expf(y0.z - ma); p[3] = expf(y0.w - ma);
        p[4] = expf(y1.x - ma); p[5] = expf(y1.y - ma);
        p[6] = expf(y1.z - ma); p[7] = expf(y1.w - ma);
        float lsa = ((p[0] + p[1]) + (p[2] + p[3])) + ((p[4] + p[5]) + (p[6] + p[7]));
        float sa = wave_sum(lsa);

        #pragma unroll
        for (int t = 0; t < 8; ++t) p[t] = p[t] / sa;   // same e/s IEEE div
        if (lane == 0)  p[0] = 1.0f;    // global col 0
        if (lane == 63) p[7] = 1.0f;    // global col 511

        // -------- exact 16th-largest via radix bit-search (p in [2^-31,1]
        // -> bits 30..28 are 011; seed 0x30000000, search 27..0).
        unsigned Ua = 0x30000000u;
        for (int b = 27; b >= 0; --b) {
            const unsigned bit = 1u << b;
            const float cfa = __uint_as_float(Ua | bit);
            int ca = 0;
            #pragma unroll
            for (int t = 0; t < 8; ++t)
                ca += __popcll(__ballot(p[t] > cfa));
            if (ca >= 16) Ua |= bit;
        }
        const float thra = __uint_as_float(Ua + 1u);

        // -------- emit 0/1 mask (non-temporal streaming stores) ----------
        native_float4 r0, r1;
        r0.x = p[0] >= thra ? 1.f : 0.f;  r0.y = p[1] >= thra ? 1.f : 0.f;
        r0.z = p[2] >= thra ? 1.f : 0.f;  r0.w = p[3] >= thra ? 1.f : 0.f;
        r1.x = p[4] >= thra ? 1.f : 0.f;  r1.y = p[5] >= thra ? 1.f : 0.f;
        r1.z = p[6] >= thra ? 1.f : 0.f;  r1.w = p[7] >= thra ? 1.f : 0.f;

        native_float4* oa = reinterpret_cast<native_float4*>(out + (size_t)ra * WDIM);
        __builtin_nontemporal_store(r0, oa + lane);
        __builtin_nontemporal_store(r1, oa + lane + 64);

        ra += 8192;
    }
}

extern "C" void kernel_launch(void* const* d_in, const int* in_sizes, int n_in,
                              void* d_out, int out_size, void* d_ws, size_t ws_size,
                              hipStream_t stream) {
    const float* x  = (const float*)d_in[0];
    const float* W1 = (const float*)d_in[1];
    const float* b1 = (const float*)d_in[2];
    const float* W2 = (const float*)d_in[3];
    const float* b2 = (const float*)d_in[4];
    const float* W3 = (const float*)d_in[5];
    const float* b3 = (const float*)d_in[6];
    float* out = (float*)d_out;

    // 1024 blocks x 512 thr = 8192 waves; 1 row/wave/iter x 8 iters = 65536.
    // (512,4): compiler VGPR cap = 256/4 = 64 (measured rule) >= 1-row demand
    // ~50-56 -> no spill; VGPR<=64 -> 8 waves/SIMD; LDS 4 blocks -> 32
    // waves/CU (HW max). Occupancy is the lever: every prior round ran 16.
    fused_mlp_topk<<<dim3(1024), dim3(THREADS), 0, stream>>>(x, W1, b1, W2, b2, W3, b3, out);
}

// Round 7
// 348.228 us; speedup vs baseline: 1.1564x; 1.1564x over previous
//
#include <hip/hip_runtime.h>
#include <math.h>

#define B_ROWS 65536
#define WDIM 512
#define HDIM 8
#define THREADS 512

// Native clang vector type — __builtin_nontemporal_{load,store} require it.
typedef float native_float4 __attribute__((ext_vector_type(4)));

// ---- DPP cross-lane (VALU pipe; avoids ds_swizzle latency/contention) ----
template<int CTRL, int ROWM>
__device__ __forceinline__ float dpp_mov(float oldv, float x) {
    return __int_as_float(__builtin_amdgcn_update_dpp(
        __float_as_int(oldv), __float_as_int(x), CTRL, ROWM, 0xF, false));
}

// Full-wave (64-lane) sum, broadcast via readlane(63). Order bit-exact vs R0.
__device__ __forceinline__ float wave_sum(float x) {
    x += dpp_mov<0x121, 0xF>(0.f, x);   // row_ror:1
    x += dpp_mov<0x122, 0xF>(0.f, x);   // row_ror:2
    x += dpp_mov<0x124, 0xF>(0.f, x);   // row_ror:4
    x += dpp_mov<0x128, 0xF>(0.f, x);   // row_ror:8  -> row-of-16 sums
    x += dpp_mov<0x142, 0xA>(0.f, x);   // row_bcast15
    x += dpp_mov<0x143, 0xC>(0.f, x);   // row_bcast31 -> lane63 = total
    return __int_as_float(__builtin_amdgcn_readlane(__float_as_int(x), 63));
}

__device__ __forceinline__ float wave_max(float x) {
    x = fmaxf(x, dpp_mov<0x121, 0xF>(-INFINITY, x));
    x = fmaxf(x, dpp_mov<0x122, 0xF>(-INFINITY, x));
    x = fmaxf(x, dpp_mov<0x124, 0xF>(-INFINITY, x));
    x = fmaxf(x, dpp_mov<0x128, 0xF>(-INFINITY, x));
    x = fmaxf(x, dpp_mov<0x142, 0xA>(-INFINITY, x));
    x = fmaxf(x, dpp_mov<0x143, 0xC>(-INFINITY, x));
    return __int_as_float(__builtin_amdgcn_readlane(__float_as_int(x), 63));
}

__device__ __forceinline__ float dot8(native_float4 a0, native_float4 a1,
                                      native_float4 b0, native_float4 b1) {
    float s = a0.x * b0.x;
    s = fmaf(a0.y, b0.y, s); s = fmaf(a0.z, b0.z, s); s = fmaf(a0.w, b0.w, s);
    s = fmaf(a1.x, b1.x, s); s = fmaf(a1.y, b1.y, s);
    s = fmaf(a1.z, b1.z, s); s = fmaf(a1.w, b1.w, s);
    return s;
}

// Round history (measured):
//  R0 (256,4)=64VGPR cap: 186us, hidden spills.  R4 (512,2)=128 cap, VGPR=100,
//  clean (FETCH 66MB, WRITE 131MB): 181us, VALUBusy 51%.  Every higher-
//  occupancy attempt (R1/R3/R5) hit the "cap == demand -> spill" wall:
//  rows-in-flight is register-file-bound at ~8/SIMD in ALL configs.
//  => lever is per-row VALU work + serial chains, not occupancy.
// R6: (1) e-space top-k: mask is scale-invariant (div by wave-uniform sa is
//  monotone), forced cols are the 2 global maxima -> search 14th largest of
//  the 510 non-forced e's, mask = e >= thr. Deletes 16 IEEE divs + the lsa
//  wave_sum per pair (exec AND critical path). (2) L3 as vector ops ->
//  v_pk_fma_f32 packing (per-element values identical).
__global__ __launch_bounds__(THREADS, 2)
void fused_mlp_topk(const float* __restrict__ x,
                    const float* __restrict__ W1,
                    const float* __restrict__ b1,
                    const float* __restrict__ W2,
                    const float* __restrict__ b2,
                    const float* __restrict__ W3,
                    const float* __restrict__ b3,
                    float* __restrict__ out)
{
    // W1 as [j][i] (8x512), W3 transposed to [k][i] (8x512): compute reads are
    // 16B/lane stride-16B ds_read_b128 (conflict-free). One read serves 2 rows.
    __shared__ __align__(16) float sW1[HDIM * WDIM];
    __shared__ __align__(16) float sW3t[HDIM * WDIM];
    __shared__ __align__(16) float sb3[WDIM];

    const int tid = threadIdx.x;
    for (int i = tid; i < HDIM * WDIM; i += THREADS) sW1[i] = W1[i];
    for (int i = tid; i < HDIM * WDIM; i += THREADS) {
        int r = i >> 3, k = i & 7;          // W3 is (512,8) row-major
        sW3t[k * WDIM + r] = W3[i];
    }
    for (int i = tid; i < WDIM; i += THREADS) sb3[i] = b3[i];
    __syncthreads();

    const int lane = tid & 63;
    const int wave_id = blockIdx.x * (THREADS / 64) + (tid >> 6);   // 8192 waves

    const native_float4* sW1v = reinterpret_cast<const native_float4*>(sW1);
    const native_float4* sW3v = reinterpret_cast<const native_float4*>(sW3t);
    const native_float4* sb3v = reinterpret_cast<const native_float4*>(sb3);

    // Preload first row pair (rows ra, ra+1), non-temporal (read-once stream).
    int ra = wave_id * 2;
    const native_float4* xpa = reinterpret_cast<const native_float4*>(x + (size_t)ra * WDIM);
    const native_float4* xpb = xpa + (WDIM / 4);
    native_float4 xa0 = __builtin_nontemporal_load(xpa + lane);
    native_float4 xa1 = __builtin_nontemporal_load(xpa + lane + 64);
    native_float4 xb0 = __builtin_nontemporal_load(xpb + lane);
    native_float4 xb1 = __builtin_nontemporal_load(xpb + lane + 64);

    #pragma unroll 1
    for (int it = 0; it < 4; ++it) {        // 8192 waves * 2 rows * 4 = 65536
        // -------- layer 1: 8 dots of 512 per row; LDS reads shared --------
        float pa[HDIM], pb[HDIM];
        #pragma unroll
        for (int j = 0; j < HDIM; ++j) {
            native_float4 w0 = sW1v[j * 128 + lane];
            native_float4 w1 = sW1v[j * 128 + lane + 64];
            pa[j] = dot8(xa0, xa1, w0, w1);
            pb[j] = dot8(xb0, xb1, w0, w1);
        }
        float h1a[HDIM], h1b[HDIM];
        #pragma unroll
        for (int j = 0; j < HDIM; ++j) {
            float sa = wave_sum(pa[j]) + b1[j];
            float sb = wave_sum(pb[j]) + b1[j];
            h1a[j] = sa > 0.f ? sa : 0.f;
            h1b[j] = sb > 0.f ? sb : 0.f;
        }

        // -------- layer 2: 8x8, wave-uniform --------
        float h2a[HDIM], h2b[HDIM];
        #pragma unroll
        for (int j = 0; j < HDIM; ++j) {
            float va = b2[j], vb = b2[j];
            #pragma unroll
            for (int k = 0; k < HDIM; ++k) {
                const float w = W2[j * HDIM + k];
                va = fmaf(w, h1a[k], va);
                vb = fmaf(w, h1b[k], vb);
            }
            h2a[j] = va > 0.f ? va : 0.f;
            h2b[j] = vb > 0.f ? vb : 0.f;
        }

        // -------- layer 3: vector form -> per-element FMA (contracted),
        // packable into v_pk_fma_f32. Values per element identical to the
        // scalar-fmaf version. --------
        native_float4 ya0 = sb3v[lane];
        native_float4 ya1 = sb3v[lane + 64];
        native_float4 yb0 = ya0, yb1 = ya1;
        #pragma unroll
        for (int k = 0; k < HDIM; ++k) {
            const float ha = h2a[k], hb = h2b[k];
            native_float4 w0 = sW3v[k * 128 + lane];
            native_float4 w1 = sW3v[k * 128 + lane + 64];
            ya0 += ha * w0;  ya1 += ha * w1;
            yb0 += hb * w0;  yb1 += hb * w1;
        }

        // -------- prefetch next pair's x (covered by softmax+radix) -------
        const int nra = ra + 16384;         // 8192 waves * 2 rows sweep
        native_float4 nxa0, nxa1, nxb0, nxb1;
        if (it < 3) {
            const native_float4* nxpa = reinterpret_cast<const native_float4*>(x + (size_t)nra * WDIM);
            const native_float4* nxpb = nxpa + (WDIM / 4);
            nxa0 = __builtin_nontemporal_load(nxpa + lane);
            nxa1 = __builtin_nontemporal_load(nxpa + lane + 64);
            nxb0 = __builtin_nontemporal_load(nxpb + lane);
            nxb1 = __builtin_nontemporal_load(nxpb + lane + 64);
        }

        // -------- softmax max + exp (e-values bit-identical to before) ----
        float lma = fmaxf(fmaxf(fmaxf(ya0.x, ya0.y), fmaxf(ya0.z, ya0.w)),
                          fmaxf(fmaxf(ya1.x, ya1.y), fmaxf(ya1.z, ya1.w)));
        float lmb = fmaxf(fmaxf(fmaxf(yb0.x, yb0.y), fmaxf(yb0.z, yb0.w)),
                          fmaxf(fmaxf(yb1.x, yb1.y), fmaxf(yb1.z, yb1.w)));
        float ma = wave_max(lma);
        float mb = wave_max(lmb);

        float ea[8], eb[8];
        ea[0] = expf(ya0.x - ma); ea[1] = expf(ya0.y - ma);
        ea[2] = expf(ya0.z - ma); ea[3] = expf(ya0.w - ma);
        ea[4] = expf(ya1.x - ma); ea[5] = expf(ya1.y - ma);
        ea[6] = expf(ya1.z - ma); ea[7] = expf(ya1.w - ma);
        eb[0] = expf(yb0.x - mb); eb[1] = expf(yb0.y - mb);
        eb[2] = expf(yb0.z - mb); eb[3] = expf(yb0.w - mb);
        eb[4] = expf(yb1.x - mb); eb[5] = expf(yb1.y - mb);
        eb[6] = expf(yb1.z - mb); eb[7] = expf(yb1.w - mb);

        // NO normalization: mask is scale-invariant. p = e/sa (sa wave-
        // uniform > 0, IEEE div monotone) => top-k set of p == top-k set of
        // e. Ref forces cols 0,511 to 1.0 = global maxima of p => they take
        // ranks 1-2; threshold = 14th largest of the remaining 510. Exclude
        // the forced slots from the count (zero them; cf > 0 always), force
        // their mask bits at emit.
        if (lane == 0)  { ea[0] = 0.f; eb[0] = 0.f; }   // global col 0
        if (lane == 63) { ea[7] = 0.f; eb[7] = 0.f; }   // global col 511

        // -------- exact 14th-largest via radix bit-search (e in [2^-31,1]
        // -> bits 30..28 are 011; seed 0x30000000, search 27..0). Two rows'
        // chains are independent -> the serial VALU->SALU latency overlaps.
        unsigned Ua = 0x30000000u, Ub = 0x30000000u;
        for (int b = 27; b >= 0; --b) {
            const unsigned bit = 1u << b;
            const float cfa = __uint_as_float(Ua | bit);
            const float cfb = __uint_as_float(Ub | bit);
            int ca = 0, cb = 0;
            #pragma unroll
            for (int t = 0; t < 8; ++t) {
                ca += __popcll(__ballot(ea[t] > cfa));
                cb += __popcll(__ballot(eb[t] > cfb));
            }
            if (ca >= 14) Ua |= bit;
            if (cb >= 14) Ub |= bit;
        }
        const float thra = __uint_as_float(Ua + 1u);
        const float thrb = __uint_as_float(Ub + 1u);

        // -------- emit 0/1 masks; forced cols overridden ----------
        native_float4 r0, r1, q0, q1;
        r0.x = ea[0] >= thra ? 1.f : 0.f;  r0.y = ea[1] >= thra ? 1.f : 0.f;
        r0.z = ea[2] >= thra ? 1.f : 0.f;  r0.w = ea[3] >= thra ? 1.f : 0.f;
        r1.x = ea[4] >= thra ? 1.f : 0.f;  r1.y = ea[5] >= thra ? 1.f : 0.f;
        r1.z = ea[6] >= thra ? 1.f : 0.f;  r1.w = ea[7] >= thra ? 1.f : 0.f;
        q0.x = eb[0] >= thrb ? 1.f : 0.f;  q0.y = eb[1] >= thrb ? 1.f : 0.f;
        q0.z = eb[2] >= thrb ? 1.f : 0.f;  q0.w = eb[3] >= thrb ? 1.f : 0.f;
        q1.x = eb[4] >= thrb ? 1.f : 0.f;  q1.y = eb[5] >= thrb ? 1.f : 0.f;
        q1.z = eb[6] >= thrb ? 1.f : 0.f;  q1.w = eb[7] >= thrb ? 1.f : 0.f;
        if (lane == 0)  { r0.x = 1.f; q0.x = 1.f; }
        if (lane == 63) { r1.w = 1.f; q1.w = 1.f; }

        native_float4* oa = reinterpret_cast<native_float4*>(out + (size_t)ra * WDIM);
        native_float4* ob = oa + (WDIM / 4);
        __builtin_nontemporal_store(r0, oa + lane);
        __builtin_nontemporal_store(r1, oa + lane + 64);
        __builtin_nontemporal_store(q0, ob + lane);
        __builtin_nontemporal_store(q1, ob + lane + 64);

        ra = nra;
        xa0 = nxa0; xa1 = nxa1; xb0 = nxb0; xb1 = nxb1;
    }
}

extern "C" void kernel_launch(void* const* d_in, const int* in_sizes, int n_in,
                              void* d_out, int out_size, void* d_ws, size_t ws_size,
                              hipStream_t stream) {
    const float* x  = (const float*)d_in[0];
    const float* W1 = (const float*)d_in[1];
    const float* b1 = (const float*)d_in[2];
    const float* W2 = (const float*)d_in[3];
    const float* b2 = (const float*)d_in[4];
    const float* W3 = (const float*)d_in[5];
    const float* b3 = (const float*)d_in[6];
    float* out = (float*)d_out;

    // 1024 blocks x 512 thr = 8192 waves; 2 rows/wave/iter x 4 iters = 65536.
    // (512,2): VGPR cap 128 (= 256/2, measured rule) >= demand ~90-100 ->
    // zero scratch (R4-proven shell). Lever this round is VALU work: e-space
    // top-k (divs + lsa-reduction deleted) + pk-FMA layer 3.
    fused_mlp_topk<<<dim3(1024), dim3(THREADS), 0, stream>>>(x, W1, b1, W2, b2, W3, b3, out);
}